// Round 6
// baseline (29.636 us; speedup 1.0000x reference)
//
#include <hip/hip_runtime.h>

// B=8, N=128, COOR=3, F=128, FILT=128
#define BB   8
#define NN   128
#define FF   128
#define KK   128

typedef float f32x4 __attribute__((ext_vector_type(4)));

// ---------------------------------------------------------------------------
// Kernel 1: AC[bn][coor][256]: cols 0..127 = A+bias/2, cols 128..255 = C+bias/2
//   A[bn,c,k] = sum_f vf[bn,c,f] * w[f,k],  C uses w[128+f,k].
// Grid 512 x 256thr. Block = 2 bn-rows. Thread = (fh = f-half, r = row,
// c4 = 4-col group): 12 FMAs per f-iter on a float4 of w (75% FMA density),
// 64 f-iters, then cross-fh LDS reduce. 131K threads -> 8 waves/CU.
// ---------------------------------------------------------------------------
__global__ __launch_bounds__(256) void k_pre(const float* __restrict__ vf,
                                             const float* __restrict__ w,
                                             const float* __restrict__ bias,
                                             float* __restrict__ ac) {
    const int bn0 = blockIdx.x * 2;
    const int tid = threadIdx.x;
    __shared__ float vfr[768];                     // 2 rows x 3 coor x 128
    __shared__ float red[128][3][4];               // fh=1 partials
    if (tid < 192) {
        ((float4*)vfr)[tid] = ((const float4*)(vf + (size_t)bn0 * 384))[tid];
    }
    __syncthreads();

    const int c4 = tid & 63;            // 4-col group: 0..31 -> A, 32..63 -> C
    const int r  = (tid >> 6) & 1;      // row within block
    const int fh = tid >> 7;            // f-half: 0 -> f 0..63, 1 -> f 64..127
    const int colbase = (c4 < 32) ? c4 * 4 : 128 + (c4 - 32) * 4;  // AC column
    const float* wbase = w + ((c4 < 32) ? (size_t)(c4 * 4)
                                        : (size_t)(FF * KK) + (c4 - 32) * 4)
                           + (size_t)fh * 64 * KK;
    const float* vr = vfr + r * 384 + fh * 64;

    float s0x=0,s0y=0,s0z=0,s0w=0, s1x=0,s1y=0,s1z=0,s1w=0, s2x=0,s2y=0,s2z=0,s2w=0;
#pragma unroll 16
    for (int ff = 0; ff < 64; ++ff) {
        const float4 w4 = *(const float4*)(wbase + (size_t)ff * KK);
        const float v0 = vr[ff], v1 = vr[128 + ff], v2 = vr[256 + ff];
        s0x = fmaf(v0, w4.x, s0x); s0y = fmaf(v0, w4.y, s0y);
        s0z = fmaf(v0, w4.z, s0z); s0w = fmaf(v0, w4.w, s0w);
        s1x = fmaf(v1, w4.x, s1x); s1y = fmaf(v1, w4.y, s1y);
        s1z = fmaf(v1, w4.z, s1z); s1w = fmaf(v1, w4.w, s1w);
        s2x = fmaf(v2, w4.x, s2x); s2y = fmaf(v2, w4.y, s2y);
        s2z = fmaf(v2, w4.z, s2z); s2w = fmaf(v2, w4.w, s2w);
    }

    const int slot = tid & 127;         // (r, c4)
    if (fh) {
        red[slot][0][0]=s0x; red[slot][0][1]=s0y; red[slot][0][2]=s0z; red[slot][0][3]=s0w;
        red[slot][1][0]=s1x; red[slot][1][1]=s1y; red[slot][1][2]=s1z; red[slot][1][3]=s1w;
        red[slot][2][0]=s2x; red[slot][2][1]=s2y; red[slot][2][2]=s2z; red[slot][2][3]=s2w;
    }
    __syncthreads();
    if (!fh) {
        const int bidx = colbase & 127;
        const float hb0 = 0.5f * bias[bidx],     hb1 = 0.5f * bias[bidx + 1];
        const float hb2 = 0.5f * bias[bidx + 2], hb3 = 0.5f * bias[bidx + 3];
        float* dst = ac + (size_t)(bn0 + r) * 768 + colbase;
        f32x4 o;
        o.x = s0x + red[slot][0][0] + hb0; o.y = s0y + red[slot][0][1] + hb1;
        o.z = s0z + red[slot][0][2] + hb2; o.w = s0w + red[slot][0][3] + hb3;
        *(f32x4*)(dst)       = o;
        o.x = s1x + red[slot][1][0] + hb0; o.y = s1y + red[slot][1][1] + hb1;
        o.z = s1z + red[slot][1][2] + hb2; o.w = s1w + red[slot][1][3] + hb3;
        *(f32x4*)(dst + 256) = o;
        o.x = s2x + red[slot][2][0] + hb0; o.y = s2y + red[slot][2][1] + hb1;
        o.z = s2z + red[slot][2][2] + hb2; o.w = s2w + red[slot][2][3] + hb3;
        *(f32x4*)(dst + 512) = o;
    }
}

// ---------------------------------------------------------------------------
// Kernel 2: out[b,i,j,k] = sum_c d[b,i,j,c] * (A'[b,i,c,k] + C'[b,j,c,k])
// Identical to R5 except: PLAIN float4 stores (A/B test vs nontemporal).
// ---------------------------------------------------------------------------
__global__ __launch_bounds__(256) void k_main(const float* __restrict__ dist,
                                              const float* __restrict__ ac,
                                              float* __restrict__ out) {
    const int bx  = blockIdx.x;
    const int b   = bx >> 8;            // 256 blocks per batch
    const int rem = bx & 255;
    const int it  = rem >> 3;           // 0..31
    const int jt  = rem & 7;            // 0..7
    const int i0  = it * 4, j0 = jt * 16;
    const int tid = threadIdx.x;

    __shared__ float dl[192];           // [ti][jj][c] = 4 x 16 x 3
    if (tid < 192) {
        const int ti = tid / 48, r = tid % 48;
        dl[tid] = dist[((size_t)(b * NN + i0 + ti) * NN + j0) * 3 + r];
    }
    __syncthreads();

    const int k4  = tid & 31;
    const int rg  = tid >> 5;
    const int ti  = rg & 3;
    const int rg4 = rg >> 2;
    const int i   = i0 + ti;

    const float4* arow = (const float4*)(ac + (size_t)(b * NN + i) * 768) + k4;
    const float4 a0 = arow[0], a1 = arow[64], a2 = arow[128];
    float* obase = out + (size_t)(b * NN + i) * NN * KK;
    const float* dlt = dl + ti * 48;

#pragma unroll
    for (int p = 0; p < 8; ++p) {
        const int jj = 2 * p + rg4;
        const int j  = j0 + jj;
        const float d0 = dlt[jj * 3], d1 = dlt[jj * 3 + 1], d2 = dlt[jj * 3 + 2];

        const float4* crow = (const float4*)(ac + (size_t)(b * NN + j) * 768)
                             + 32 + k4;          // +128 floats: C-half
        const float4 c0 = crow[0], c1 = crow[64], c2 = crow[128];

        f32x4 r;
        r.x = fmaf(d0, a0.x + c0.x, fmaf(d1, a1.x + c1.x, d2 * (a2.x + c2.x)));
        r.y = fmaf(d0, a0.y + c0.y, fmaf(d1, a1.y + c1.y, d2 * (a2.y + c2.y)));
        r.z = fmaf(d0, a0.z + c0.z, fmaf(d1, a1.z + c1.z, d2 * (a2.z + c2.z)));
        r.w = fmaf(d0, a0.w + c0.w, fmaf(d1, a1.w + c1.w, d2 * (a2.w + c2.w)));

        *(f32x4*)(obase + (size_t)j * KK + k4 * 4) = r;
    }
}

// ---------------------------------------------------------------------------
// Fallback (only if ws_size < 3 MB): fused, recomputes C per j. Slow but correct.
// ---------------------------------------------------------------------------
__global__ __launch_bounds__(256) void k_fused_slow(const float* __restrict__ vf,
                                                    const float* __restrict__ dist,
                                                    const float* __restrict__ w,
                                                    const float* __restrict__ bias,
                                                    float* __restrict__ out) {
    const int bi  = blockIdx.x;           // b*NN + i
    const int b   = bi >> 7;
    const int tid = threadIdx.x;
    __shared__ float arow[384];
    __shared__ float crow[384];

    for (int idx = tid; idx < 384; idx += 256) {
        const int c = idx >> 7, k = idx & 127;
        const float* v = vf + (size_t)bi * 384 + c * 128;
        float s = 0.f;
        for (int f = 0; f < 128; ++f) s = fmaf(v[f], w[f * 128 + k], s);
        arow[idx] = s;
    }
    __syncthreads();

    for (int j = 0; j < NN; ++j) {
        for (int idx = tid; idx < 384; idx += 256) {
            const int c = idx >> 7, k = idx & 127;
            const float* v = vf + (size_t)(b * NN + j) * 384 + c * 128;
            float s = 0.f;
            for (int f = 0; f < 128; ++f) s = fmaf(v[f], w[(128 + f) * 128 + k], s);
            crow[idx] = s;
        }
        __syncthreads();
        if (tid < 128) {
            const float* dj = dist + ((size_t)bi * NN + j) * 3;
            const float d0 = dj[0], d1 = dj[1], d2 = dj[2];
            const float sd = d0 + d1 + d2;
            const float r = fmaf(d0, arow[tid] + crow[tid],
                            fmaf(d1, arow[128 + tid] + crow[128 + tid],
                            fmaf(d2, arow[256 + tid] + crow[256 + tid], sd * bias[tid])));
            out[((size_t)bi * NN + j) * 128 + tid] = r;
        }
        __syncthreads();
    }
}

extern "C" void kernel_launch(void* const* d_in, const int* in_sizes, int n_in,
                              void* d_out, int out_size, void* d_ws, size_t ws_size,
                              hipStream_t stream) {
    const float* vf   = (const float*)d_in[0];   // [8,128,3,128]
    const float* dist = (const float*)d_in[1];   // [8,128,128,3]
    const float* w    = (const float*)d_in[2];   // [256,128]
    const float* bias = (const float*)d_in[3];   // [128]
    float* out = (float*)d_out;                  // [8,128,128,128]

    const size_t need = (size_t)BB * NN * 3 * 256 * sizeof(float);  // 3 MB
    if (ws_size >= need) {
        float* ac = (float*)d_ws;
        k_pre<<<512, 256, 0, stream>>>(vf, w, bias, ac);
        k_main<<<2048, 256, 0, stream>>>(dist, ac, out);
    } else {
        k_fused_slow<<<BB * NN, 256, 0, stream>>>(vf, dist, w, bias, out);
    }
}

// Round 7
// 29.018 us; speedup vs baseline: 1.0213x; 1.0213x over previous
//
#include <hip/hip_runtime.h>

// B=8, N=128, COOR=3, F=128, FILT=128
#define BB   8
#define NN   128
#define FF   128
#define KK   128

typedef float f32x4 __attribute__((ext_vector_type(4)));

// ---------------------------------------------------------------------------
// Kernel 1: AC[bn][c][2x128]: per (bn,c) row: [A+bias/2 (128) | C+bias/2 (128)]
//   A[bn,c,k] = sum_f vf[bn,c,f] * w[f,k],  C uses w[128+f,k].
// Bias fold: out = sum_c d_c*((A_c+b/2)+(C_c+b/2)) == sum_c d_c*(A+C) + sd*b.
// (R5 version — known-good config from the 27.4 us runs)
// ---------------------------------------------------------------------------
__global__ __launch_bounds__(256) void k_pre(const float* __restrict__ vf,
                                             const float* __restrict__ w,
                                             const float* __restrict__ bias,
                                             float* __restrict__ ac) {
    const int bn0 = blockIdx.x * 2;
    const int tid = threadIdx.x;
    __shared__ float vfr[768];                     // 2 rows x 3 coor x 128
    if (tid < 192) {
        ((float4*)vfr)[tid] = ((const float4*)(vf + (size_t)bn0 * 384))[tid];
    }
    __syncthreads();

    const int col  = tid & 127;
    const int half = tid >> 7;                     // 0 = A-half, 1 = C-half
    const float* wcol = w + half * (FF * KK) + col;

    float a00 = 0.f, a01 = 0.f, a02 = 0.f;
    float a10 = 0.f, a11 = 0.f, a12 = 0.f;
#pragma unroll 16
    for (int f = 0; f < FF; ++f) {
        const float wv = wcol[f * KK];
        a00 = fmaf(wv, vfr[f],       a00);
        a01 = fmaf(wv, vfr[128 + f], a01);
        a02 = fmaf(wv, vfr[256 + f], a02);
        a10 = fmaf(wv, vfr[384 + f], a10);
        a11 = fmaf(wv, vfr[512 + f], a11);
        a12 = fmaf(wv, vfr[640 + f], a12);
    }
    const float hb = 0.5f * bias[col];
    float* dst = ac + (size_t)bn0 * 768 + half * 128 + col;
    dst[0]    = a00 + hb;  dst[256]  = a01 + hb;  dst[512]  = a02 + hb;
    dst[768]  = a10 + hb;  dst[1024] = a11 + hb;  dst[1280] = a12 + hb;
}

// ---------------------------------------------------------------------------
// Kernel 2: out[b,i,j,k] = sum_c d[b,i,j,c] * (A'[b,i,c,k] + C'[b,j,c,k])
// Grid 2048 (4i x 16j tiles), 256 thr. NEW vs R5: the block's 16 C-rows
// (24 KB) are staged in LDS ONCE (single L2 read per block) instead of each
// i-wave-group re-reading them through a thrashing L1 (4x L2 traffic).
// NT stores keep the 64 MB output stream out of L2. jt in low 3 bits of
// blockIdx for XCD affinity on the shared C-rows.
// ---------------------------------------------------------------------------
__global__ __launch_bounds__(256) void k_main(const float* __restrict__ dist,
                                              const float* __restrict__ ac,
                                              float* __restrict__ out) {
    const int bx  = blockIdx.x;
    const int b   = bx >> 8;            // 256 blocks per batch
    const int rem = bx & 255;
    const int it  = rem >> 3;           // 0..31
    const int jt  = rem & 7;            // 0..7
    const int i0  = it * 4, j0 = jt * 16;
    const int tid = threadIdx.x;

    __shared__ float cl[16 * 384];      // [row][c][128] C-halves, 24 KB
    __shared__ float dl[192];           // [ti][jj][c] = 4 x 16 x 3

    // Stage C-tile: 1536 float4, 6 per thread. Per row: 3 slices of 32 f4.
    const f32x4* acv = (const f32x4*)ac;
    for (int idx = tid; idx < 1536; idx += 256) {
        const int row = idx / 96, rem96 = idx % 96;
        const int c = rem96 >> 5, q = rem96 & 31;
        ((f32x4*)cl)[idx] = acv[(size_t)(b * NN + j0 + row) * 192 + c * 64 + 32 + q];
    }
    if (tid < 192) {
        const int ti = tid / 48, r = tid % 48;
        dl[tid] = dist[((size_t)(b * NN + i0 + ti) * NN + j0) * 3 + r];
    }
    __syncthreads();

    const int k4  = tid & 31;
    const int rg  = tid >> 5;
    const int ti  = rg & 3;
    const int rg4 = rg >> 2;
    const int i   = i0 + ti;

    const float4* arow = (const float4*)(ac + (size_t)(b * NN + i) * 768) + k4;
    const float4 a0 = arow[0], a1 = arow[64], a2 = arow[128];
    float* obase = out + (size_t)(b * NN + i) * NN * KK;
    const float* dlt = dl + ti * 48;
    const f32x4* clv = (const f32x4*)cl;

#pragma unroll
    for (int p = 0; p < 8; ++p) {
        const int jj = 2 * p + rg4;
        const int j  = j0 + jj;
        const float d0 = dlt[jj * 3], d1 = dlt[jj * 3 + 1], d2 = dlt[jj * 3 + 2];

        const f32x4 c0 = clv[jj * 96 + k4];
        const f32x4 c1 = clv[jj * 96 + 32 + k4];
        const f32x4 c2 = clv[jj * 96 + 64 + k4];

        f32x4 r;
        r.x = fmaf(d0, a0.x + c0.x, fmaf(d1, a1.x + c1.x, d2 * (a2.x + c2.x)));
        r.y = fmaf(d0, a0.y + c0.y, fmaf(d1, a1.y + c1.y, d2 * (a2.y + c2.y)));
        r.z = fmaf(d0, a0.z + c0.z, fmaf(d1, a1.z + c1.z, d2 * (a2.z + c2.z)));
        r.w = fmaf(d0, a0.w + c0.w, fmaf(d1, a1.w + c1.w, d2 * (a2.w + c2.w)));

        __builtin_nontemporal_store(r, (f32x4*)(obase + (size_t)j * KK + k4 * 4));
    }
}

// ---------------------------------------------------------------------------
// Fallback (only if ws_size < 3 MB): fused, recomputes C per j. Slow but correct.
// ---------------------------------------------------------------------------
__global__ __launch_bounds__(256) void k_fused_slow(const float* __restrict__ vf,
                                                    const float* __restrict__ dist,
                                                    const float* __restrict__ w,
                                                    const float* __restrict__ bias,
                                                    float* __restrict__ out) {
    const int bi  = blockIdx.x;           // b*NN + i
    const int b   = bi >> 7;
    const int tid = threadIdx.x;
    __shared__ float arow[384];
    __shared__ float crow[384];

    for (int idx = tid; idx < 384; idx += 256) {
        const int c = idx >> 7, k = idx & 127;
        const float* v = vf + (size_t)bi * 384 + c * 128;
        float s = 0.f;
        for (int f = 0; f < 128; ++f) s = fmaf(v[f], w[f * 128 + k], s);
        arow[idx] = s;
    }
    __syncthreads();

    for (int j = 0; j < NN; ++j) {
        for (int idx = tid; idx < 384; idx += 256) {
            const int c = idx >> 7, k = idx & 127;
            const float* v = vf + (size_t)(b * NN + j) * 384 + c * 128;
            float s = 0.f;
            for (int f = 0; f < 128; ++f) s = fmaf(v[f], w[(128 + f) * 128 + k], s);
            crow[idx] = s;
        }
        __syncthreads();
        if (tid < 128) {
            const float* dj = dist + ((size_t)bi * NN + j) * 3;
            const float d0 = dj[0], d1 = dj[1], d2 = dj[2];
            const float sd = d0 + d1 + d2;
            const float r = fmaf(d0, arow[tid] + crow[tid],
                            fmaf(d1, arow[128 + tid] + crow[128 + tid],
                            fmaf(d2, arow[256 + tid] + crow[256 + tid], sd * bias[tid])));
            out[((size_t)bi * NN + j) * 128 + tid] = r;
        }
        __syncthreads();
    }
}

extern "C" void kernel_launch(void* const* d_in, const int* in_sizes, int n_in,
                              void* d_out, int out_size, void* d_ws, size_t ws_size,
                              hipStream_t stream) {
    const float* vf   = (const float*)d_in[0];   // [8,128,3,128]
    const float* dist = (const float*)d_in[1];   // [8,128,128,3]
    const float* w    = (const float*)d_in[2];   // [256,128]
    const float* bias = (const float*)d_in[3];   // [128]
    float* out = (float*)d_out;                  // [8,128,128,128]

    const size_t need = (size_t)BB * NN * 3 * 256 * sizeof(float);  // 3 MB
    if (ws_size >= need) {
        float* ac = (float*)d_ws;
        k_pre<<<512, 256, 0, stream>>>(vf, w, bias, ac);
        k_main<<<2048, 256, 0, stream>>>(dist, ac, out);
    } else {
        k_fused_slow<<<BB * NN, 256, 0, stream>>>(vf, dist, w, bias, out);
    }
}